// Round 9
// baseline (394.904 us; speedup 1.0000x reference)
//
#include <hip/hip_runtime.h>
#include <math.h>
#include <float.h>

#define Mdim 64
#define Ldim 32
#define Pdim 100
#define NCdim 400
#define EVALS_PER_P (NCdim + 1)            // 401
#define EVALS_PER_WAVE 128                 // 2 per lane (packed fp32)
#define WAVES_PER_M 314                    // ceil(40100/128)
#define BLOCKS_PER_M 79                    // ceil(314/4), 4 waves/block
#define NPTS (Mdim * Pdim)                 // 6400
#define TWO_PI_F 6.28318530717958647692f
#define INV_2PI_F 0.15915494309189535f
#define NLOG2E_F (-1.4426950408889634f)
#define LOG2_10TH (-3.3219280948873623f)   // log2(0.1)

typedef float v2 __attribute__((ext_vector_type(2)));

__device__ __forceinline__ v2 mk2(float a, float b) { v2 r; r.x = a; r.y = b; return r; }
__device__ __forceinline__ v2 sel2(bool cx, bool cy, v2 a, v2 b) {
    return mk2(cx ? a.x : b.x, cy ? a.y : b.y);
}

// Per-layer, m-uniform, omega-free parameters. 32 B -> 2x ds_read_b128.
struct alignas(16) LayerP {
    float dm;        // layer thickness
    float inv_a2;    // 1/a^2
    float inv_b2;    // 1/b^2
    float b2two;     // 2*b^2
    float rm;        // rho
    float inv_rm;    // 1/rho
    float inv_rho2;  // 1/rho^2
    float rho2;      // rho^2
};

// Order-preserving float<->uint maps (for atomicMax/Min on float values).
__device__ __forceinline__ unsigned ord_encode(float f) {
    unsigned u = __float_as_uint(f);
    return (u & 0x80000000u) ? ~u : (u | 0x80000000u);
}
__device__ __forceinline__ float ord_decode(unsigned u) {
    unsigned v = (u & 0x80000000u) ? (u & 0x7FFFFFFFu) : ~u;
    return __uint_as_float(v);
}

// One layer of the Dunkin recursion on a packed eval pair.
// x = ra2*w and z = rb2*y identities eliminate the x/z select chains:
//   lt: x = -ra*sp  = ra2*(sp/ra)      (ra2 < 0, ra^2 = -ra2)
//   gt: x = +ra*se  = ra2*(se/ra)      (ra2 > 0, ra^2 = +ra2)
// so xy = ra2*wy, wz = rb2*wy, xz = ra2*wz, cqx = ra2*cqw, cpz = rb2*cpy.
template <bool RENORM>
__device__ __forceinline__ void layer_step(const LayerP& L,
                                           v2 wvno2, v2 wvno4, v2 tneg, v2 om2, v2 invom2,
                                           v2& e0, v2& e1, v2& e2, v2& e3, v2& e4)
{
    const float dm = L.dm;

    const v2 ra2 = wvno2 - om2 * L.inv_a2;   // sign = regime
    const v2 rb2 = wvno2 - om2 * L.inv_b2;

    // rsq replaces sqrt+rcp (trans-pipe 8 -> 4 ops per pair-layer).
    const v2 inv_ra = mk2(__builtin_amdgcn_rsqf(fabsf(ra2.x)),
                          __builtin_amdgcn_rsqf(fabsf(ra2.y)));
    const v2 inv_rb = mk2(__builtin_amdgcn_rsqf(fabsf(rb2.x)),
                          __builtin_amdgcn_rsqf(fabsf(rb2.y)));
    const v2 ra = mk2(fabsf(ra2.x), fabsf(ra2.y)) * inv_ra;
    const v2 rb = mk2(fabsf(rb2.x), fabsf(rb2.y)) * inv_rb;
    const v2 pp = ra * dm;
    const v2 qq = rb * dm;
    const v2 gammk = L.b2two * invom2;
    const v2 gam   = gammk * wvno2;

    // Raw HW transcendentals with shared packed argument scaling.
    const v2 ppr = pp * INV_2PI_F;           // v_sin/v_cos take revolutions
    const v2 qqr = qq * INV_2PI_F;
    const v2 sp = mk2(__builtin_amdgcn_sinf(ppr.x), __builtin_amdgcn_sinf(ppr.y));
    const v2 cp = mk2(__builtin_amdgcn_cosf(ppr.x), __builtin_amdgcn_cosf(ppr.y));
    const v2 sq = mk2(__builtin_amdgcn_sinf(qqr.x), __builtin_amdgcn_sinf(qqr.y));
    const v2 cq = mk2(__builtin_amdgcn_cosf(qqr.x), __builtin_amdgcn_cosf(qqr.y));
    const v2 pe = pp * NLOG2E_F;             // exp(-p) = exp2(-p*log2e)
    const v2 qe = qq * NLOG2E_F;
    const v2 e_p = mk2(__builtin_amdgcn_exp2f(pe.x), __builtin_amdgcn_exp2f(pe.y));
    const v2 e_q = mk2(__builtin_amdgcn_exp2f(qe.x), __builtin_amdgcn_exp2f(qe.y));

    const v2 fac_p = e_p * e_p;              // exp(-2p)
    const v2 fac_q = e_q * e_q;
    const v2 cosp_e = 0.5f * fac_p + 0.5f;
    const v2 sinp_e = -0.5f * fac_p + 0.5f;
    const v2 cosq_e = 0.5f * fac_q + 0.5f;
    const v2 sinq_e = -0.5f * fac_q + 0.5f;

    const bool lt_ax = ra2.x < 0.0f, lt_ay = ra2.y < 0.0f;
    const bool lt_bx = rb2.x < 0.0f, lt_by = rb2.y < 0.0f;

    const v2 one = mk2(1.0f, 1.0f);
    const v2 cosp = sel2(lt_ax, lt_ay, cp, cosp_e);   // eq regime: cosp_e == 1
    const v2 w = sel2(lt_ax, lt_ay, sp, sinp_e) * inv_ra;
    const v2 cosq = sel2(lt_bx, lt_by, cq, cosq_e);
    const v2 y = sel2(lt_bx, lt_by, sq, sinq_e) * inv_rb;
    const v2 a0 = sel2(lt_ax, lt_ay, one, e_p) * sel2(lt_bx, lt_by, one, e_q);

    const v2 cpcq = cosp * cosq;
    const v2 cpy  = cosp * y;
    const v2 cqw  = cosq * w;
    const v2 wy   = w * y;
    const v2 cpz  = rb2 * cpy;
    const v2 cqx  = ra2 * cqw;
    const v2 wz   = rb2 * wy;
    const v2 xy   = ra2 * wy;
    const v2 xz   = ra2 * wz;

    // ---- _dnka (c20/c21/c23/c24 folded into et2 = tneg*e2) ----
    const v2 gamm1 = gam - 1.0f;
    const v2 twgm1 = gam + gamm1;
    const v2 gmgmk = gam * gammk;
    const v2 gmgm1 = gam * gamm1;
    const v2 gm1sq = gamm1 * gamm1;
    const v2 a0pq  = a0 - cpcq;

    const v2 c00 = cpcq - 2.0f * gmgm1 * a0pq - gmgmk * xz - wvno2 * gm1sq * wy;
    const v2 c01 = (wvno2 * cpy - cqx) * L.inv_rm;
    const v2 c02 = -(twgm1 * a0pq + gammk * xz + wvno2 * gamm1 * wy) * L.inv_rm;
    const v2 c03 = (cpz - wvno2 * cqw) * L.inv_rm;
    const v2 c04 = -(2.0f * wvno2 * a0pq + xz + wvno4 * wy) * L.inv_rho2;
    const v2 c10 = (gmgmk * cpz - gm1sq * cqw) * L.rm;
    const v2 c11 = cpcq;
    const v2 c12 = gammk * cpz - gamm1 * cqw;
    const v2 c13 = -wz;
    const v2 c30 = (gm1sq * cpy - gmgmk * cqx) * L.rm;
    const v2 c31 = -xy;
    const v2 c32 = gamm1 * cpy - gammk * cqx;
    const v2 c40 = -(2.0f * gmgmk * gm1sq * a0pq + gmgmk * gmgmk * xz
                     + gm1sq * gm1sq * wy) * L.rho2;
    const v2 c42 = -(gammk * gamm1 * twgm1 * a0pq + gam * gammk * gammk * xz
                     + gamm1 * gm1sq * wy) * L.rm;
    const v2 c22 = a0 + 2.0f * (cpcq - c00);

    const v2 et2 = tneg * e2;   // folds the tneg-scaled row-2 coefficients

    // ---- ee = e . ca ----
    const v2 ee0 = e0 * c00 + e1 * c10 + et2 * c42 + e3 * c30 + e4 * c40;
    const v2 ee1 = e0 * c01 + e1 * c11 + et2 * c32 + e3 * c31 + e4 * c30;
    const v2 ee2 = e0 * c02 + e1 * c12 + e2  * c22 + e3 * c32 + e4 * c42;
    const v2 ee3 = e0 * c03 + e1 * c13 + et2 * c12 + e3 * c11 + e4 * c10;
    const v2 ee4 = e0 * c04 + e1 * c03 + et2 * c02 + e3 * c01 + e4 * c00;

    if constexpr (RENORM) {
        float t1x = fmaxf(fmaxf(fabsf(ee0.x), fabsf(ee1.x)), fabsf(ee2.x));
        t1x = fmaxf(t1x, fmaxf(fabsf(ee3.x), fabsf(ee4.x)));
        float t1y = fmaxf(fmaxf(fabsf(ee0.y), fabsf(ee1.y)), fabsf(ee2.y));
        t1y = fmaxf(t1y, fmaxf(fabsf(ee3.y), fabsf(ee4.y)));
        t1x = fmaxf(t1x, 1e-30f);
        t1y = fmaxf(t1y, 1e-30f);
        const v2 inv = mk2(__builtin_amdgcn_rcpf(t1x), __builtin_amdgcn_rcpf(t1y));
        e0 = ee0 * inv;
        e1 = ee1 * inv;
        e2 = ee2 * inv;
        e3 = ee3 * inv;
        e4 = ee4 * inv;
    } else {
        e0 = ee0; e1 = ee1; e2 = ee2; e3 = ee3; e4 = ee4;
    }
}

// Packed Dunkin-recursion determinant: TWO independent evals per lane.
__device__ __forceinline__ v2 dltar4_pk(v2 wvno2, v2 om2, v2 invom2,
                                        const LayerP* __restrict__ slay)
{
    const v2 wvno4 = wvno2 * wvno2;
    const v2 tneg  = -2.0f * wvno2;

    // ---- halfspace init ----
    const LayerP H = slay[Ldim - 1];
    const v2 ra2h = wvno2 - om2 * H.inv_a2;
    const v2 rb2h = wvno2 - om2 * H.inv_b2;
    const v2 ra_h = mk2(__builtin_amdgcn_sqrtf(fabsf(ra2h.x)),
                        __builtin_amdgcn_sqrtf(fabsf(ra2h.y)));
    const v2 rb_h = mk2(__builtin_amdgcn_sqrtf(fabsf(rb2h.x)),
                        __builtin_amdgcn_sqrtf(fabsf(rb2h.y)));
    const v2 gammk_h = H.b2two * invom2;
    const v2 gam_h   = gammk_h * wvno2;
    const v2 gamm1_h = gam_h - 1.0f;
    const v2 rarb_h  = ra_h * rb_h;
    v2 e0 = H.rho2 * (gamm1_h * gamm1_h - gam_h * gammk_h * rarb_h);
    v2 e1 = -H.rm * ra_h;
    v2 e2 = H.rm * (gamm1_h - gammk_h * rarb_h);
    v2 e3 = H.rm * rb_h;
    v2 e4 = wvno2 - rarb_h;

    // l = 30 (even -> renorm), then 15 pairs (29,28) .. (1,0).
    layer_step<true>(slay[Ldim - 2], wvno2, wvno4, tneg, om2, invom2,
                     e0, e1, e2, e3, e4);
    for (int l = Ldim - 3; l >= 1; l -= 2) {
        layer_step<false>(slay[l],     wvno2, wvno4, tneg, om2, invom2,
                          e0, e1, e2, e3, e4);
        layer_step<true> (slay[l - 1], wvno2, wvno4, tneg, om2, invom2,
                          e0, e1, e2, e3, e4);
    }
    return e0;
}

// Workspace: mxU[NPTS], mnU[NPTS] (ordered uints), e00f[NPTS], cnt[Mdim].
__global__ void init_ws_kernel(unsigned* __restrict__ mxU, unsigned* __restrict__ mnU,
                               unsigned* __restrict__ cnt)
{
    int i = blockIdx.x * blockDim.x + threadIdx.x;
    if (i < NPTS) {
        mxU[i] = 0u;           // ordered-encoding of -inf side
        mnU[i] = 0xFFFFFFFFu;  // ordered-encoding of +inf side
    }
    if (i < Mdim) cnt[i] = 0u;
}

// Main kernel: TWO evals per lane + fused epilogue (last wave per m).
__global__ __launch_bounds__(256, 5)
void disp_kernel(const float* __restrict__ vlist, const float* __restrict__ tlist,
                 const float* __restrict__ dth,  const float* __restrict__ bvel,
                 const float* __restrict__ Clist,
                 unsigned* __restrict__ mxU, unsigned* __restrict__ mnU,
                 float* __restrict__ e00f, unsigned* __restrict__ cnt,
                 float* __restrict__ out)
{
    __shared__ LayerP slay[Ldim];

    const int bid = blockIdx.x;
    const int m   = bid / BLOCKS_PER_M;
    const int wb  = bid - m * BLOCKS_PER_M;
    const int tid  = threadIdx.x;
    const int wid  = tid >> 6;
    const int lane = tid & 63;
    const int wv   = wb * 4 + wid;            // wave index within m

    if (tid < Ldim) {
        const float bb = bvel[m * Ldim + tid];
        const float b2 = bb * bb;
        const float b3 = b2 * bb;
        const float b4 = b2 * b2;
        const float aa = 0.9409f + 2.0947f * bb - 0.8206f * b2
                         + 0.2683f * b3 - 0.0251f * b4;
        const float a2 = aa * aa;
        const float a3 = a2 * aa;
        const float a4 = a2 * a2;
        const float a5 = a4 * aa;
        const float rr = 1.6612f * aa - 0.4721f * a2 + 0.0671f * a3
                         - 0.0043f * a4 + 0.000106f * a5;
        LayerP Lp;
        Lp.dm       = dth[m * Ldim + tid];
        Lp.inv_a2   = 1.0f / (aa * aa);
        Lp.inv_b2   = 1.0f / (bb * bb);
        Lp.b2two    = 2.0f * bb * bb;
        Lp.rm       = rr;
        Lp.inv_rm   = 1.0f / rr;
        Lp.inv_rho2 = 1.0f / (rr * rr);
        Lp.rho2     = rr * rr;
        slay[tid] = Lp;
    }
    __syncthreads();

    if (wv >= WAVES_PER_M) return;            // idle waves (after barrier)

    // Decode (p, c) for both evals of this lane.
    const int S  = wv * EVALS_PER_WAVE;
    const int p0 = S / EVALS_PER_P;           // magic-mul const divide
    const int c0 = S - p0 * EVALS_PER_P;

    int cx = c0 + lane;
    const bool crx = cx >= EVALS_PER_P;
    const int px = p0 + (crx ? 1 : 0);
    cx = crx ? cx - EVALS_PER_P : cx;
    const bool validx = px < Pdim;

    int cy = c0 + 64 + lane;
    const bool cry = cy >= EVALS_PER_P;
    const int py = p0 + (cry ? 1 : 0);
    cy = cry ? cy - EVALS_PER_P : cy;
    const bool validy = py < Pdim;

    const int mpx = m * Pdim + (validx ? px : 0);
    const int mpy = m * Pdim + (validy ? py : 0);
    const float omx = fmaxf(TWO_PI_F / tlist[mpx], 1.0e-4f);
    const float omy = fmaxf(TWO_PI_F / tlist[mpy], 1.0e-4f);
    const bool isCx = cx < NCdim;
    const bool isCy = cy < NCdim;
    const float denx = isCx ? Clist[cx] : vlist[mpx];
    const float deny = isCy ? Clist[cy] : vlist[mpy];
    const float wvx = omx / denx;
    const float wvy = omy / deny;

    const v2 om2    = mk2(omx * omx, omy * omy);
    const v2 invom2 = mk2(__builtin_amdgcn_rcpf(om2.x), __builtin_amdgcn_rcpf(om2.y));
    const v2 wvno2  = mk2(wvx * wvx, wvy * wvy);

    const v2 det = dltar4_pk(wvno2, om2, invom2, slay);

    // e00 stores (exactly one lane/eval per (m,p) has c == NCdim).
    if (validx && !isCx) e00f[m * Pdim + px] = det.x;
    if (validy && !isCy) e00f[m * Pdim + py] = det.y;

    // Segmented reduction over the wave's <=2 p-segments (pA/pB wave-uniform).
    const int pA = p0;
    const int pB = p0 + ((c0 + EVALS_PER_WAVE - 1) >= EVALS_PER_P ? 1 : 0);

    {
        const bool inAx = validx && isCx && (px == pA);
        const bool inAy = validy && isCy && (py == pA);
        float mxA = fmaxf(inAx ? det.x : -FLT_MAX, inAy ? det.y : -FLT_MAX);
        float mnA = fminf(inAx ? det.x :  FLT_MAX, inAy ? det.y :  FLT_MAX);
        for (int off = 32; off >= 1; off >>= 1) {
            mxA = fmaxf(mxA, __shfl_xor(mxA, off));
            mnA = fminf(mnA, __shfl_xor(mnA, off));
        }
        if (lane == 0 && pA < Pdim) {
            atomicMax(&mxU[m * Pdim + pA], ord_encode(mxA));
            atomicMin(&mnU[m * Pdim + pA], ord_encode(mnA));
        }
    }
    if (pB != pA) {                           // wave-uniform branch
        const bool inBx = validx && isCx && (px == pB);
        const bool inBy = validy && isCy && (py == pB);
        float mxB = fmaxf(inBx ? det.x : -FLT_MAX, inBy ? det.y : -FLT_MAX);
        float mnB = fminf(inBx ? det.x :  FLT_MAX, inBy ? det.y :  FLT_MAX);
        for (int off = 32; off >= 1; off >>= 1) {
            mxB = fmaxf(mxB, __shfl_xor(mxB, off));
            mnB = fminf(mnB, __shfl_xor(mnB, off));
        }
        if (lane == 0 && pB < Pdim) {
            atomicMax(&mxU[m * Pdim + pB], ord_encode(mxB));
            atomicMin(&mnU[m * Pdim + pB], ord_encode(mnB));
        }
    }

    // ---- fused epilogue: last wave to finish for this m computes out[m] ----
    __threadfence();                          // release all stores/atomics above
    unsigned old = 0u;
    if (lane == 0) old = atomicAdd(&cnt[m], 1u);
    const int last = __shfl((lane == 0 && old == WAVES_PER_M - 1) ? 1 : 0, 0);
    if (last) {
        __threadfence();                      // acquire side

        float acc = 0.0f;
        for (int p = lane; p < Pdim; p += 64) {
            const int i = m * Pdim + p;
            const unsigned umx = __hip_atomic_load(&mxU[i], __ATOMIC_RELAXED,
                                                   __HIP_MEMORY_SCOPE_AGENT);
            const unsigned umn = __hip_atomic_load(&mnU[i], __ATOMIC_RELAXED,
                                                   __HIP_MEMORY_SCOPE_AGENT);
            const float e00v = __hip_atomic_load(&e00f[i], __ATOMIC_RELAXED,
                                                 __HIP_MEMORY_SCOPE_AGENT);
            const float rng = ord_decode(umx) - ord_decode(umn);
            const float en  = e00v / rng;
            acc += 1.0f - __builtin_amdgcn_exp2f(fabsf(en) * LOG2_10TH);
        }

        float damp = 0.0f;
        if (lane < Ldim) {
            const float bb    = bvel[m * Ldim + lane];
            const float bprev = bvel[m * Ldim + ((lane == 0) ? 0 : lane - 1)];
            const float bnext = bvel[m * Ldim + ((lane == Ldim - 1) ? Ldim - 1 : lane + 1)];
            float tval;
            if (lane == 0)             tval = bb - bnext;
            else if (lane == Ldim - 1) tval = bb - bprev;
            else                       tval = 2.0f * bb - bprev - bnext;
            damp = fabsf(tval * (1.0f / (float)Ldim));
        }

        float tot = fmaf(acc, 1.0f / (float)Pdim, damp);
        for (int off = 32; off >= 1; off >>= 1)
            tot += __shfl_xor(tot, off);
        if (lane == 0) out[m] = tot;
    }
}

extern "C" void kernel_launch(void* const* d_in, const int* in_sizes, int n_in,
                              void* d_out, int out_size, void* d_ws, size_t ws_size,
                              hipStream_t stream)
{
    const float* vlist = (const float*)d_in[0];
    const float* tlist = (const float*)d_in[1];
    const float* dth   = (const float*)d_in[2];
    const float* bvel  = (const float*)d_in[3];
    const float* Clist = (const float*)d_in[4];
    float* out = (float*)d_out;

    unsigned* mxU = (unsigned*)d_ws;
    unsigned* mnU = mxU + NPTS;
    float*    e00f = (float*)(mnU + NPTS);
    unsigned* cnt  = (unsigned*)(e00f + NPTS);

    hipLaunchKernelGGL(init_ws_kernel, dim3((NPTS + 255) / 256), dim3(256), 0, stream,
                       mxU, mnU, cnt);
    hipLaunchKernelGGL(disp_kernel, dim3(Mdim * BLOCKS_PER_M), dim3(256), 0, stream,
                       vlist, tlist, dth, bvel, Clist, mxU, mnU, e00f, cnt, out);
}

// Round 10
// 252.684 us; speedup vs baseline: 1.5628x; 1.5628x over previous
//
#include <hip/hip_runtime.h>
#include <math.h>
#include <float.h>

#define Mdim 64
#define Ldim 32
#define Pdim 100
#define NCdim 400
#define EVALS_PER_P (NCdim + 1)            // 401
#define EVALS_PER_WAVE 128                 // 2 per lane (packed fp32)
#define WAVES_PER_M 314                    // ceil(40100/128)
#define BLOCKS_PER_M 79                    // ceil(314/4), 4 waves/block
#define NPTS (Mdim * Pdim)                 // 6400
#define TWO_PI_F 6.28318530717958647692f
#define INV_2PI_F 0.15915494309189535f
#define NLOG2E_F (-1.4426950408889634f)
#define LOG2_10TH (-3.3219280948873623f)   // log2(0.1)

typedef float v2 __attribute__((ext_vector_type(2)));

__device__ __forceinline__ v2 mk2(float a, float b) { v2 r; r.x = a; r.y = b; return r; }
__device__ __forceinline__ v2 sel2(bool cx, bool cy, v2 a, v2 b) {
    return mk2(cx ? a.x : b.x, cy ? a.y : b.y);
}

// Per-layer, m-uniform, omega-free parameters. 32 B -> 2x ds_read_b128.
struct alignas(16) LayerP {
    float dm;        // layer thickness
    float inv_a2;    // 1/a^2
    float inv_b2;    // 1/b^2
    float b2two;     // 2*b^2
    float rm;        // rho
    float inv_rm;    // 1/rho
    float inv_rho2;  // 1/rho^2
    float rho2;      // rho^2
};

// Order-preserving float<->uint maps (for atomicMax/Min on float values).
__device__ __forceinline__ unsigned ord_encode(float f) {
    unsigned u = __float_as_uint(f);
    return (u & 0x80000000u) ? ~u : (u | 0x80000000u);
}
__device__ __forceinline__ float ord_decode(unsigned u) {
    unsigned v = (u & 0x80000000u) ? (u & 0x7FFFFFFFu) : ~u;
    return __uint_as_float(v);
}

// One layer of the Dunkin recursion on a packed eval pair.
// x = ra2*w and z = rb2*y identities eliminate the x/z select chains:
//   lt: x = -ra*sp = ra2*(sp/ra)   (ra2<0);  gt: x = +ra*se = ra2*(se/ra).
// so xy = ra2*wy, wz = rb2*wy, xz = ra2*wz, cqx = ra2*cqw, cpz = rb2*cpy.
template <bool RENORM>
__device__ __forceinline__ void layer_step(const LayerP& L,
                                           v2 wvno2, v2 wvno4, v2 tneg, v2 om2, v2 invom2,
                                           v2& e0, v2& e1, v2& e2, v2& e3, v2& e4)
{
    const float dm = L.dm;

    const v2 ra2 = wvno2 - om2 * L.inv_a2;   // sign = regime
    const v2 rb2 = wvno2 - om2 * L.inv_b2;

    // rsq replaces sqrt+rcp (trans-pipe 8 -> 4 ops per pair-layer).
    const v2 inv_ra = mk2(__builtin_amdgcn_rsqf(fabsf(ra2.x)),
                          __builtin_amdgcn_rsqf(fabsf(ra2.y)));
    const v2 inv_rb = mk2(__builtin_amdgcn_rsqf(fabsf(rb2.x)),
                          __builtin_amdgcn_rsqf(fabsf(rb2.y)));
    const v2 ra = mk2(fabsf(ra2.x), fabsf(ra2.y)) * inv_ra;
    const v2 rb = mk2(fabsf(rb2.x), fabsf(rb2.y)) * inv_rb;
    const v2 pp = ra * dm;
    const v2 qq = rb * dm;
    const v2 gammk = L.b2two * invom2;
    const v2 gam   = gammk * wvno2;

    // Raw HW transcendentals with shared packed argument scaling.
    const v2 ppr = pp * INV_2PI_F;           // v_sin/v_cos take revolutions
    const v2 qqr = qq * INV_2PI_F;
    const v2 sp = mk2(__builtin_amdgcn_sinf(ppr.x), __builtin_amdgcn_sinf(ppr.y));
    const v2 cp = mk2(__builtin_amdgcn_cosf(ppr.x), __builtin_amdgcn_cosf(ppr.y));
    const v2 sq = mk2(__builtin_amdgcn_sinf(qqr.x), __builtin_amdgcn_sinf(qqr.y));
    const v2 cq = mk2(__builtin_amdgcn_cosf(qqr.x), __builtin_amdgcn_cosf(qqr.y));
    const v2 pe = pp * NLOG2E_F;             // exp(-p) = exp2(-p*log2e)
    const v2 qe = qq * NLOG2E_F;
    const v2 e_p = mk2(__builtin_amdgcn_exp2f(pe.x), __builtin_amdgcn_exp2f(pe.y));
    const v2 e_q = mk2(__builtin_amdgcn_exp2f(qe.x), __builtin_amdgcn_exp2f(qe.y));

    const v2 fac_p = e_p * e_p;              // exp(-2p)
    const v2 fac_q = e_q * e_q;
    const v2 cosp_e = 0.5f * fac_p + 0.5f;
    const v2 sinp_e = -0.5f * fac_p + 0.5f;
    const v2 cosq_e = 0.5f * fac_q + 0.5f;
    const v2 sinq_e = -0.5f * fac_q + 0.5f;

    const bool lt_ax = ra2.x < 0.0f, lt_ay = ra2.y < 0.0f;
    const bool lt_bx = rb2.x < 0.0f, lt_by = rb2.y < 0.0f;

    const v2 one = mk2(1.0f, 1.0f);
    const v2 cosp = sel2(lt_ax, lt_ay, cp, cosp_e);   // eq regime: cosp_e == 1
    const v2 w = sel2(lt_ax, lt_ay, sp, sinp_e) * inv_ra;
    const v2 cosq = sel2(lt_bx, lt_by, cq, cosq_e);
    const v2 y = sel2(lt_bx, lt_by, sq, sinq_e) * inv_rb;
    const v2 a0 = sel2(lt_ax, lt_ay, one, e_p) * sel2(lt_bx, lt_by, one, e_q);

    const v2 cpcq = cosp * cosq;
    const v2 cpy  = cosp * y;
    const v2 cqw  = cosq * w;
    const v2 wy   = w * y;
    const v2 cpz  = rb2 * cpy;
    const v2 cqx  = ra2 * cqw;
    const v2 wz   = rb2 * wy;
    const v2 xy   = ra2 * wy;
    const v2 xz   = ra2 * wz;

    // ---- _dnka (c20/c21/c23/c24 folded into et2 = tneg*e2) ----
    const v2 gamm1 = gam - 1.0f;
    const v2 twgm1 = gam + gamm1;
    const v2 gmgmk = gam * gammk;
    const v2 gmgm1 = gam * gamm1;
    const v2 gm1sq = gamm1 * gamm1;
    const v2 a0pq  = a0 - cpcq;

    const v2 c00 = cpcq - 2.0f * gmgm1 * a0pq - gmgmk * xz - wvno2 * gm1sq * wy;
    const v2 c01 = (wvno2 * cpy - cqx) * L.inv_rm;
    const v2 c02 = -(twgm1 * a0pq + gammk * xz + wvno2 * gamm1 * wy) * L.inv_rm;
    const v2 c03 = (cpz - wvno2 * cqw) * L.inv_rm;
    const v2 c04 = -(2.0f * wvno2 * a0pq + xz + wvno4 * wy) * L.inv_rho2;
    const v2 c10 = (gmgmk * cpz - gm1sq * cqw) * L.rm;
    const v2 c11 = cpcq;
    const v2 c12 = gammk * cpz - gamm1 * cqw;
    const v2 c13 = -wz;
    const v2 c30 = (gm1sq * cpy - gmgmk * cqx) * L.rm;
    const v2 c31 = -xy;
    const v2 c32 = gamm1 * cpy - gammk * cqx;
    const v2 c40 = -(2.0f * gmgmk * gm1sq * a0pq + gmgmk * gmgmk * xz
                     + gm1sq * gm1sq * wy) * L.rho2;
    const v2 c42 = -(gammk * gamm1 * twgm1 * a0pq + gam * gammk * gammk * xz
                     + gamm1 * gm1sq * wy) * L.rm;
    const v2 c22 = a0 + 2.0f * (cpcq - c00);

    const v2 et2 = tneg * e2;   // folds the tneg-scaled row-2 coefficients

    // ---- ee = e . ca ----
    const v2 ee0 = e0 * c00 + e1 * c10 + et2 * c42 + e3 * c30 + e4 * c40;
    const v2 ee1 = e0 * c01 + e1 * c11 + et2 * c32 + e3 * c31 + e4 * c30;
    const v2 ee2 = e0 * c02 + e1 * c12 + e2  * c22 + e3 * c32 + e4 * c42;
    const v2 ee3 = e0 * c03 + e1 * c13 + et2 * c12 + e3 * c11 + e4 * c10;
    const v2 ee4 = e0 * c04 + e1 * c03 + et2 * c02 + e3 * c01 + e4 * c00;

    if constexpr (RENORM) {
        float t1x = fmaxf(fmaxf(fabsf(ee0.x), fabsf(ee1.x)), fabsf(ee2.x));
        t1x = fmaxf(t1x, fmaxf(fabsf(ee3.x), fabsf(ee4.x)));
        float t1y = fmaxf(fmaxf(fabsf(ee0.y), fabsf(ee1.y)), fabsf(ee2.y));
        t1y = fmaxf(t1y, fmaxf(fabsf(ee3.y), fabsf(ee4.y)));
        t1x = fmaxf(t1x, 1e-30f);
        t1y = fmaxf(t1y, 1e-30f);
        const v2 inv = mk2(__builtin_amdgcn_rcpf(t1x), __builtin_amdgcn_rcpf(t1y));
        e0 = ee0 * inv;
        e1 = ee1 * inv;
        e2 = ee2 * inv;
        e3 = ee3 * inv;
        e4 = ee4 * inv;
    } else {
        e0 = ee0; e1 = ee1; e2 = ee2; e3 = ee3; e4 = ee4;
    }
}

// Packed Dunkin-recursion determinant: TWO independent evals per lane.
__device__ __forceinline__ v2 dltar4_pk(v2 wvno2, v2 om2, v2 invom2,
                                        const LayerP* __restrict__ slay)
{
    const v2 wvno4 = wvno2 * wvno2;
    const v2 tneg  = -2.0f * wvno2;

    // ---- halfspace init ----
    const LayerP H = slay[Ldim - 1];
    const v2 ra2h = wvno2 - om2 * H.inv_a2;
    const v2 rb2h = wvno2 - om2 * H.inv_b2;
    const v2 ra_h = mk2(__builtin_amdgcn_sqrtf(fabsf(ra2h.x)),
                        __builtin_amdgcn_sqrtf(fabsf(ra2h.y)));
    const v2 rb_h = mk2(__builtin_amdgcn_sqrtf(fabsf(rb2h.x)),
                        __builtin_amdgcn_sqrtf(fabsf(rb2h.y)));
    const v2 gammk_h = H.b2two * invom2;
    const v2 gam_h   = gammk_h * wvno2;
    const v2 gamm1_h = gam_h - 1.0f;
    const v2 rarb_h  = ra_h * rb_h;
    v2 e0 = H.rho2 * (gamm1_h * gamm1_h - gam_h * gammk_h * rarb_h);
    v2 e1 = -H.rm * ra_h;
    v2 e2 = H.rm * (gamm1_h - gammk_h * rarb_h);
    v2 e3 = H.rm * rb_h;
    v2 e4 = wvno2 - rarb_h;

    // l = 30 (even -> renorm), then 15 pairs (29,28) .. (1,0).
    layer_step<true>(slay[Ldim - 2], wvno2, wvno4, tneg, om2, invom2,
                     e0, e1, e2, e3, e4);
    for (int l = Ldim - 3; l >= 1; l -= 2) {
        layer_step<false>(slay[l],     wvno2, wvno4, tneg, om2, invom2,
                          e0, e1, e2, e3, e4);
        layer_step<true> (slay[l - 1], wvno2, wvno4, tneg, om2, invom2,
                          e0, e1, e2, e3, e4);
    }
    return e0;
}

// Workspace layout: mxU[NPTS], mnU[NPTS] (ordered uints), e00f[NPTS] floats.
__global__ void init_ws_kernel(unsigned* __restrict__ mxU, unsigned* __restrict__ mnU)
{
    int i = blockIdx.x * blockDim.x + threadIdx.x;
    if (i < NPTS) {
        mxU[i] = 0u;           // ordered-encoding of -inf side
        mnU[i] = 0xFFFFFFFFu;  // ordered-encoding of +inf side
    }
}

// Main kernel: TWO evals per lane. Block = 4 waves, all same m.
// Wave wv covers flat evals [S, S+128), lane handles j = S+lane (.x) and
// j = S+64+lane (.y). 128 < 401 -> at most 2 p-segments, pA/pB wave-uniform.
__global__ __launch_bounds__(256, 5)
void disp_kernel(const float* __restrict__ vlist, const float* __restrict__ tlist,
                 const float* __restrict__ dth,  const float* __restrict__ bvel,
                 const float* __restrict__ Clist,
                 unsigned* __restrict__ mxU, unsigned* __restrict__ mnU,
                 float* __restrict__ e00f)
{
    __shared__ LayerP slay[Ldim];

    const int bid = blockIdx.x;
    const int m   = bid / BLOCKS_PER_M;
    const int wb  = bid - m * BLOCKS_PER_M;
    const int tid  = threadIdx.x;
    const int wid  = tid >> 6;
    const int lane = tid & 63;
    const int wv   = wb * 4 + wid;            // wave index within m

    if (tid < Ldim) {
        const float bb = bvel[m * Ldim + tid];
        const float b2 = bb * bb;
        const float b3 = b2 * bb;
        const float b4 = b2 * b2;
        const float aa = 0.9409f + 2.0947f * bb - 0.8206f * b2
                         + 0.2683f * b3 - 0.0251f * b4;
        const float a2 = aa * aa;
        const float a3 = a2 * aa;
        const float a4 = a2 * a2;
        const float a5 = a4 * aa;
        const float rr = 1.6612f * aa - 0.4721f * a2 + 0.0671f * a3
                         - 0.0043f * a4 + 0.000106f * a5;
        LayerP Lp;
        Lp.dm       = dth[m * Ldim + tid];
        Lp.inv_a2   = 1.0f / (aa * aa);
        Lp.inv_b2   = 1.0f / (bb * bb);
        Lp.b2two    = 2.0f * bb * bb;
        Lp.rm       = rr;
        Lp.inv_rm   = 1.0f / rr;
        Lp.inv_rho2 = 1.0f / (rr * rr);
        Lp.rho2     = rr * rr;
        slay[tid] = Lp;
    }
    __syncthreads();

    if (wv >= WAVES_PER_M) return;            // idle waves (after barrier)

    // Decode (p, c) for both evals of this lane.
    const int S  = wv * EVALS_PER_WAVE;
    const int p0 = S / EVALS_PER_P;           // magic-mul const divide
    const int c0 = S - p0 * EVALS_PER_P;

    int cx = c0 + lane;
    const bool crx = cx >= EVALS_PER_P;
    const int px = p0 + (crx ? 1 : 0);
    cx = crx ? cx - EVALS_PER_P : cx;
    const bool validx = px < Pdim;

    int cy = c0 + 64 + lane;
    const bool cry = cy >= EVALS_PER_P;
    const int py = p0 + (cry ? 1 : 0);
    cy = cry ? cy - EVALS_PER_P : cy;
    const bool validy = py < Pdim;

    const int mpx = m * Pdim + (validx ? px : 0);
    const int mpy = m * Pdim + (validy ? py : 0);
    const float omx = fmaxf(TWO_PI_F / tlist[mpx], 1.0e-4f);
    const float omy = fmaxf(TWO_PI_F / tlist[mpy], 1.0e-4f);
    const bool isCx = cx < NCdim;
    const bool isCy = cy < NCdim;
    const float denx = isCx ? Clist[cx] : vlist[mpx];
    const float deny = isCy ? Clist[cy] : vlist[mpy];
    const float wvx = omx / denx;
    const float wvy = omy / deny;

    const v2 om2    = mk2(omx * omx, omy * omy);
    const v2 invom2 = mk2(__builtin_amdgcn_rcpf(om2.x), __builtin_amdgcn_rcpf(om2.y));
    const v2 wvno2  = mk2(wvx * wvx, wvy * wvy);

    const v2 det = dltar4_pk(wvno2, om2, invom2, slay);

    // e00 stores (exactly one lane/eval per (m,p) has c == NCdim).
    if (validx && !isCx) e00f[m * Pdim + px] = det.x;
    if (validy && !isCy) e00f[m * Pdim + py] = det.y;

    // Segmented reduction over the wave's <=2 p-segments (pA/pB wave-uniform).
    const int pA = p0;
    const int pB = p0 + ((c0 + EVALS_PER_WAVE - 1) >= EVALS_PER_P ? 1 : 0);

    {
        const bool inAx = validx && isCx && (px == pA);
        const bool inAy = validy && isCy && (py == pA);
        float mxA = fmaxf(inAx ? det.x : -FLT_MAX, inAy ? det.y : -FLT_MAX);
        float mnA = fminf(inAx ? det.x :  FLT_MAX, inAy ? det.y :  FLT_MAX);
        for (int off = 32; off >= 1; off >>= 1) {
            mxA = fmaxf(mxA, __shfl_xor(mxA, off));
            mnA = fminf(mnA, __shfl_xor(mnA, off));
        }
        if (lane == 0 && pA < Pdim) {
            atomicMax(&mxU[m * Pdim + pA], ord_encode(mxA));
            atomicMin(&mnU[m * Pdim + pA], ord_encode(mnA));
        }
    }
    if (pB != pA) {                           // wave-uniform branch
        const bool inBx = validx && isCx && (px == pB);
        const bool inBy = validy && isCy && (py == pB);
        float mxB = fmaxf(inBx ? det.x : -FLT_MAX, inBy ? det.y : -FLT_MAX);
        float mnB = fminf(inBx ? det.x :  FLT_MAX, inBy ? det.y :  FLT_MAX);
        for (int off = 32; off >= 1; off >>= 1) {
            mxB = fmaxf(mxB, __shfl_xor(mxB, off));
            mnB = fminf(mnB, __shfl_xor(mnB, off));
        }
        if (lane == 0 && pB < Pdim) {
            atomicMax(&mxU[m * Pdim + pB], ord_encode(mxB));
            atomicMin(&mnU[m * Pdim + pB], ord_encode(mnB));
        }
    }
}

// Epilogue: one wave per m. Sums the 100 per-p terms + damping, writes out[m].
__global__ __launch_bounds__(64)
void epilogue_kernel(const unsigned* __restrict__ mxU, const unsigned* __restrict__ mnU,
                     const float* __restrict__ e00f, const float* __restrict__ bvel,
                     float* __restrict__ out)
{
    const int m    = blockIdx.x;
    const int lane = threadIdx.x;

    float acc = 0.0f;
    for (int p = lane; p < Pdim; p += 64) {
        const int i = m * Pdim + p;
        const float mx = ord_decode(mxU[i]);
        const float mn = ord_decode(mnU[i]);
        const float en = e00f[i] / (mx - mn);
        acc += 1.0f - __builtin_amdgcn_exp2f(fabsf(en) * LOG2_10TH); // 1-0.1^|en|
    }

    // damping term
    float damp = 0.0f;
    if (lane < Ldim) {
        const float bb    = bvel[m * Ldim + lane];
        const float bprev = bvel[m * Ldim + ((lane == 0) ? 0 : lane - 1)];
        const float bnext = bvel[m * Ldim + ((lane == Ldim - 1) ? Ldim - 1 : lane + 1)];
        float tval;
        if (lane == 0)             tval = bb - bnext;
        else if (lane == Ldim - 1) tval = bb - bprev;
        else                       tval = 2.0f * bb - bprev - bnext;
        damp = fabsf(tval * (1.0f / (float)Ldim));
    }

    float tot = fmaf(acc, 1.0f / (float)Pdim, damp);
    for (int off = 32; off >= 1; off >>= 1)
        tot += __shfl_xor(tot, off);
    if (lane == 0) out[m] = tot;
}

extern "C" void kernel_launch(void* const* d_in, const int* in_sizes, int n_in,
                              void* d_out, int out_size, void* d_ws, size_t ws_size,
                              hipStream_t stream)
{
    const float* vlist = (const float*)d_in[0];
    const float* tlist = (const float*)d_in[1];
    const float* dth   = (const float*)d_in[2];
    const float* bvel  = (const float*)d_in[3];
    const float* Clist = (const float*)d_in[4];
    float* out = (float*)d_out;

    unsigned* mxU = (unsigned*)d_ws;
    unsigned* mnU = mxU + NPTS;
    float*    e00f = (float*)(mnU + NPTS);

    hipLaunchKernelGGL(init_ws_kernel, dim3((NPTS + 255) / 256), dim3(256), 0, stream,
                       mxU, mnU);
    hipLaunchKernelGGL(disp_kernel, dim3(Mdim * BLOCKS_PER_M), dim3(256), 0, stream,
                       vlist, tlist, dth, bvel, Clist, mxU, mnU, e00f);
    hipLaunchKernelGGL(epilogue_kernel, dim3(Mdim), dim3(64), 0, stream,
                       mxU, mnU, e00f, bvel, out);
}

// Round 11
// 251.661 us; speedup vs baseline: 1.5692x; 1.0041x over previous
//
#include <hip/hip_runtime.h>
#include <math.h>
#include <float.h>

#define Mdim 64
#define Ldim 32
#define Pdim 100
#define NCdim 400
#define EVALS_PER_P (NCdim + 1)            // 401
#define EVALS_PER_WAVE 128                 // 2 per lane (packed fp32)
#define WAVES_PER_M 314                    // ceil(40100/128)
#define BLOCKS_PER_M 79                    // ceil(314/4), 4 waves/block
#define NPTS (Mdim * Pdim)                 // 6400
#define WSLOT (Mdim * WAVES_PER_M)         // 20096 part slots
#define TWO_PI_F 6.28318530717958647692f
#define INV_2PI_F 0.15915494309189535f
#define NLOG2E_F (-1.4426950408889634f)
#define LOG2_10TH (-3.3219280948873623f)   // log2(0.1)

typedef float v2 __attribute__((ext_vector_type(2)));

__device__ __forceinline__ v2 mk2(float a, float b) { v2 r; r.x = a; r.y = b; return r; }
__device__ __forceinline__ v2 sel2(bool cx, bool cy, v2 a, v2 b) {
    return mk2(cx ? a.x : b.x, cy ? a.y : b.y);
}

// Per-layer, m-uniform, omega-free parameters. 32 B -> 2x ds_read_b128.
struct alignas(16) LayerP {
    float dm;        // layer thickness
    float inv_a2;    // 1/a^2
    float inv_b2;    // 1/b^2
    float b2two;     // 2*b^2
    float rm;        // rho
    float inv_rm;    // 1/rho
    float inv_rho2;  // 1/rho^2
    float rho2;      // rho^2
};

// One layer of the Dunkin recursion on a packed eval pair.
// x = ra2*w and z = rb2*y identities eliminate the x/z select chains.
template <bool RENORM>
__device__ __forceinline__ void layer_step(const LayerP& L,
                                           v2 wvno2, v2 wvno4, v2 tneg, v2 om2, v2 invom2,
                                           v2& e0, v2& e1, v2& e2, v2& e3, v2& e4)
{
    const float dm = L.dm;

    const v2 ra2 = wvno2 - om2 * L.inv_a2;   // sign = regime
    const v2 rb2 = wvno2 - om2 * L.inv_b2;

    // rsq replaces sqrt+rcp.
    const v2 inv_ra = mk2(__builtin_amdgcn_rsqf(fabsf(ra2.x)),
                          __builtin_amdgcn_rsqf(fabsf(ra2.y)));
    const v2 inv_rb = mk2(__builtin_amdgcn_rsqf(fabsf(rb2.x)),
                          __builtin_amdgcn_rsqf(fabsf(rb2.y)));
    const v2 ra = mk2(fabsf(ra2.x), fabsf(ra2.y)) * inv_ra;
    const v2 rb = mk2(fabsf(rb2.x), fabsf(rb2.y)) * inv_rb;
    const v2 pp = ra * dm;
    const v2 qq = rb * dm;
    const v2 gammk = L.b2two * invom2;
    const v2 gam   = gammk * wvno2;

    // Raw HW transcendentals with shared packed argument scaling.
    const v2 ppr = pp * INV_2PI_F;           // v_sin/v_cos take revolutions
    const v2 qqr = qq * INV_2PI_F;
    const v2 sp = mk2(__builtin_amdgcn_sinf(ppr.x), __builtin_amdgcn_sinf(ppr.y));
    const v2 cp = mk2(__builtin_amdgcn_cosf(ppr.x), __builtin_amdgcn_cosf(ppr.y));
    const v2 sq = mk2(__builtin_amdgcn_sinf(qqr.x), __builtin_amdgcn_sinf(qqr.y));
    const v2 cq = mk2(__builtin_amdgcn_cosf(qqr.x), __builtin_amdgcn_cosf(qqr.y));
    const v2 pe = pp * NLOG2E_F;             // exp(-p) = exp2(-p*log2e)
    const v2 qe = qq * NLOG2E_F;
    const v2 e_p = mk2(__builtin_amdgcn_exp2f(pe.x), __builtin_amdgcn_exp2f(pe.y));
    const v2 e_q = mk2(__builtin_amdgcn_exp2f(qe.x), __builtin_amdgcn_exp2f(qe.y));

    const v2 fac_p = e_p * e_p;              // exp(-2p)
    const v2 fac_q = e_q * e_q;
    const v2 cosp_e = 0.5f * fac_p + 0.5f;
    const v2 sinp_e = -0.5f * fac_p + 0.5f;
    const v2 cosq_e = 0.5f * fac_q + 0.5f;
    const v2 sinq_e = -0.5f * fac_q + 0.5f;

    const bool lt_ax = ra2.x < 0.0f, lt_ay = ra2.y < 0.0f;
    const bool lt_bx = rb2.x < 0.0f, lt_by = rb2.y < 0.0f;

    const v2 one = mk2(1.0f, 1.0f);
    const v2 cosp = sel2(lt_ax, lt_ay, cp, cosp_e);   // eq regime: cosp_e == 1
    const v2 w = sel2(lt_ax, lt_ay, sp, sinp_e) * inv_ra;
    const v2 cosq = sel2(lt_bx, lt_by, cq, cosq_e);
    const v2 y = sel2(lt_bx, lt_by, sq, sinq_e) * inv_rb;
    const v2 a0 = sel2(lt_ax, lt_ay, one, e_p) * sel2(lt_bx, lt_by, one, e_q);

    const v2 cpcq = cosp * cosq;
    const v2 cpy  = cosp * y;
    const v2 cqw  = cosq * w;
    const v2 wy   = w * y;
    const v2 cpz  = rb2 * cpy;
    const v2 cqx  = ra2 * cqw;
    const v2 wz   = rb2 * wy;
    const v2 xy   = ra2 * wy;
    const v2 xz   = ra2 * wz;

    // ---- _dnka (c20/c21/c23/c24 folded into et2 = tneg*e2) ----
    const v2 gamm1 = gam - 1.0f;
    const v2 twgm1 = gam + gamm1;
    const v2 gmgmk = gam * gammk;
    const v2 gmgm1 = gam * gamm1;
    const v2 gm1sq = gamm1 * gamm1;
    const v2 a0pq  = a0 - cpcq;

    const v2 c00 = cpcq - 2.0f * gmgm1 * a0pq - gmgmk * xz - wvno2 * gm1sq * wy;
    const v2 c01 = (wvno2 * cpy - cqx) * L.inv_rm;
    const v2 c02 = -(twgm1 * a0pq + gammk * xz + wvno2 * gamm1 * wy) * L.inv_rm;
    const v2 c03 = (cpz - wvno2 * cqw) * L.inv_rm;
    const v2 c04 = -(2.0f * wvno2 * a0pq + xz + wvno4 * wy) * L.inv_rho2;
    const v2 c10 = (gmgmk * cpz - gm1sq * cqw) * L.rm;
    const v2 c11 = cpcq;
    const v2 c12 = gammk * cpz - gamm1 * cqw;
    const v2 c13 = -wz;
    const v2 c30 = (gm1sq * cpy - gmgmk * cqx) * L.rm;
    const v2 c31 = -xy;
    const v2 c32 = gamm1 * cpy - gammk * cqx;
    const v2 c40 = -(2.0f * gmgmk * gm1sq * a0pq + gmgmk * gmgmk * xz
                     + gm1sq * gm1sq * wy) * L.rho2;
    const v2 c42 = -(gammk * gamm1 * twgm1 * a0pq + gam * gammk * gammk * xz
                     + gamm1 * gm1sq * wy) * L.rm;
    const v2 c22 = a0 + 2.0f * (cpcq - c00);

    const v2 et2 = tneg * e2;   // folds the tneg-scaled row-2 coefficients

    // ---- ee = e . ca ----
    const v2 ee0 = e0 * c00 + e1 * c10 + et2 * c42 + e3 * c30 + e4 * c40;
    const v2 ee1 = e0 * c01 + e1 * c11 + et2 * c32 + e3 * c31 + e4 * c30;
    const v2 ee2 = e0 * c02 + e1 * c12 + e2  * c22 + e3 * c32 + e4 * c42;
    const v2 ee3 = e0 * c03 + e1 * c13 + et2 * c12 + e3 * c11 + e4 * c10;
    const v2 ee4 = e0 * c04 + e1 * c03 + et2 * c02 + e3 * c01 + e4 * c00;

    if constexpr (RENORM) {
        float t1x = fmaxf(fmaxf(fabsf(ee0.x), fabsf(ee1.x)), fabsf(ee2.x));
        t1x = fmaxf(t1x, fmaxf(fabsf(ee3.x), fabsf(ee4.x)));
        float t1y = fmaxf(fmaxf(fabsf(ee0.y), fabsf(ee1.y)), fabsf(ee2.y));
        t1y = fmaxf(t1y, fmaxf(fabsf(ee3.y), fabsf(ee4.y)));
        t1x = fmaxf(t1x, 1e-30f);
        t1y = fmaxf(t1y, 1e-30f);
        const v2 inv = mk2(__builtin_amdgcn_rcpf(t1x), __builtin_amdgcn_rcpf(t1y));
        e0 = ee0 * inv;
        e1 = ee1 * inv;
        e2 = ee2 * inv;
        e3 = ee3 * inv;
        e4 = ee4 * inv;
    } else {
        e0 = ee0; e1 = ee1; e2 = ee2; e3 = ee3; e4 = ee4;
    }
}

// Packed Dunkin-recursion determinant: TWO independent evals per lane.
__device__ __forceinline__ v2 dltar4_pk(v2 wvno2, v2 om2, v2 invom2,
                                        const LayerP* __restrict__ slay)
{
    const v2 wvno4 = wvno2 * wvno2;
    const v2 tneg  = -2.0f * wvno2;

    // ---- halfspace init ----
    const LayerP H = slay[Ldim - 1];
    const v2 ra2h = wvno2 - om2 * H.inv_a2;
    const v2 rb2h = wvno2 - om2 * H.inv_b2;
    const v2 ra_h = mk2(__builtin_amdgcn_sqrtf(fabsf(ra2h.x)),
                        __builtin_amdgcn_sqrtf(fabsf(ra2h.y)));
    const v2 rb_h = mk2(__builtin_amdgcn_sqrtf(fabsf(rb2h.x)),
                        __builtin_amdgcn_sqrtf(fabsf(rb2h.y)));
    const v2 gammk_h = H.b2two * invom2;
    const v2 gam_h   = gammk_h * wvno2;
    const v2 gamm1_h = gam_h - 1.0f;
    const v2 rarb_h  = ra_h * rb_h;
    v2 e0 = H.rho2 * (gamm1_h * gamm1_h - gam_h * gammk_h * rarb_h);
    v2 e1 = -H.rm * ra_h;
    v2 e2 = H.rm * (gamm1_h - gammk_h * rarb_h);
    v2 e3 = H.rm * rb_h;
    v2 e4 = wvno2 - rarb_h;

    // l = 30 (even -> renorm), then 15 pairs (29,28) .. (1,0).
    layer_step<true>(slay[Ldim - 2], wvno2, wvno4, tneg, om2, invom2,
                     e0, e1, e2, e3, e4);
    for (int l = Ldim - 3; l >= 1; l -= 2) {
        layer_step<false>(slay[l],     wvno2, wvno4, tneg, om2, invom2,
                          e0, e1, e2, e3, e4);
        layer_step<true> (slay[l - 1], wvno2, wvno4, tneg, om2, invom2,
                          e0, e1, e2, e3, e4);
    }
    return e0;
}

// Main kernel: TWO evals per lane. Block = 4 waves, all same m.
// Wave wv covers flat evals [S, S+128). Per-wave segment max/min go to
// DEDICATED slots (pAmx/pAmn for the wave's first p, pBmx/pBmn for the
// crossed-into p) -- plain stores, no init kernel, no atomics. Sentinel
// +/-FLT_MAX are the neutral elements for partially-covering waves.
__global__ __launch_bounds__(256, 5)
void disp_kernel(const float* __restrict__ vlist, const float* __restrict__ tlist,
                 const float* __restrict__ dth,  const float* __restrict__ bvel,
                 const float* __restrict__ Clist,
                 float* __restrict__ pAmx, float* __restrict__ pAmn,
                 float* __restrict__ pBmx, float* __restrict__ pBmn,
                 float* __restrict__ e00f)
{
    __shared__ LayerP slay[Ldim];

    const int bid = blockIdx.x;
    const int m   = bid / BLOCKS_PER_M;
    const int wb  = bid - m * BLOCKS_PER_M;
    const int tid  = threadIdx.x;
    const int wid  = tid >> 6;
    const int lane = tid & 63;
    const int wv   = wb * 4 + wid;            // wave index within m

    if (tid < Ldim) {
        const float bb = bvel[m * Ldim + tid];
        const float b2 = bb * bb;
        const float b3 = b2 * bb;
        const float b4 = b2 * b2;
        const float aa = 0.9409f + 2.0947f * bb - 0.8206f * b2
                         + 0.2683f * b3 - 0.0251f * b4;
        const float a2 = aa * aa;
        const float a3 = a2 * aa;
        const float a4 = a2 * a2;
        const float a5 = a4 * aa;
        const float rr = 1.6612f * aa - 0.4721f * a2 + 0.0671f * a3
                         - 0.0043f * a4 + 0.000106f * a5;
        LayerP Lp;
        Lp.dm       = dth[m * Ldim + tid];
        Lp.inv_a2   = 1.0f / (aa * aa);
        Lp.inv_b2   = 1.0f / (bb * bb);
        Lp.b2two    = 2.0f * bb * bb;
        Lp.rm       = rr;
        Lp.inv_rm   = 1.0f / rr;
        Lp.inv_rho2 = 1.0f / (rr * rr);
        Lp.rho2     = rr * rr;
        slay[tid] = Lp;
    }
    __syncthreads();

    if (wv >= WAVES_PER_M) return;            // idle waves (after barrier)

    // Decode (p, c) for both evals of this lane.
    const int S  = wv * EVALS_PER_WAVE;
    const int p0 = S / EVALS_PER_P;           // magic-mul const divide
    const int c0 = S - p0 * EVALS_PER_P;

    int cx = c0 + lane;
    const bool crx = cx >= EVALS_PER_P;
    const int px = p0 + (crx ? 1 : 0);
    cx = crx ? cx - EVALS_PER_P : cx;
    const bool validx = px < Pdim;

    int cy = c0 + 64 + lane;
    const bool cry = cy >= EVALS_PER_P;
    const int py = p0 + (cry ? 1 : 0);
    cy = cry ? cy - EVALS_PER_P : cy;
    const bool validy = py < Pdim;

    const int mpx = m * Pdim + (validx ? px : 0);
    const int mpy = m * Pdim + (validy ? py : 0);
    const float omx = fmaxf(TWO_PI_F / tlist[mpx], 1.0e-4f);
    const float omy = fmaxf(TWO_PI_F / tlist[mpy], 1.0e-4f);
    const bool isCx = cx < NCdim;
    const bool isCy = cy < NCdim;
    const float denx = isCx ? Clist[cx] : vlist[mpx];
    const float deny = isCy ? Clist[cy] : vlist[mpy];
    const float wvx = omx * __builtin_amdgcn_rcpf(denx);
    const float wvy = omy * __builtin_amdgcn_rcpf(deny);

    const v2 om2    = mk2(omx * omx, omy * omy);
    const v2 invom2 = mk2(__builtin_amdgcn_rcpf(om2.x), __builtin_amdgcn_rcpf(om2.y));
    const v2 wvno2  = mk2(wvx * wvx, wvy * wvy);

    const v2 det = dltar4_pk(wvno2, om2, invom2, slay);

    // e00 stores (exactly one lane/eval per (m,p) has c == NCdim).
    if (validx && !isCx) e00f[m * Pdim + px] = det.x;
    if (validy && !isCy) e00f[m * Pdim + py] = det.y;

    // Segmented reduction over the wave's <=2 p-segments (pA/pB wave-uniform).
    const int pA = p0;
    const int pB = p0 + ((c0 + EVALS_PER_WAVE - 1) >= EVALS_PER_P ? 1 : 0);
    const int slot = m * WAVES_PER_M + wv;

    {
        const bool inAx = validx && isCx && (px == pA);
        const bool inAy = validy && isCy && (py == pA);
        float mxA = fmaxf(inAx ? det.x : -FLT_MAX, inAy ? det.y : -FLT_MAX);
        float mnA = fminf(inAx ? det.x :  FLT_MAX, inAy ? det.y :  FLT_MAX);
        for (int off = 32; off >= 1; off >>= 1) {
            mxA = fmaxf(mxA, __shfl_xor(mxA, off));
            mnA = fminf(mnA, __shfl_xor(mnA, off));
        }
        if (lane == 0) {
            pAmx[slot] = mxA;
            pAmn[slot] = mnA;
        }
    }
    if (pB != pA) {                           // wave-uniform branch
        const bool inBx = validx && isCx && (px == pB);
        const bool inBy = validy && isCy && (py == pB);
        float mxB = fmaxf(inBx ? det.x : -FLT_MAX, inBy ? det.y : -FLT_MAX);
        float mnB = fminf(inBx ? det.x :  FLT_MAX, inBy ? det.y :  FLT_MAX);
        for (int off = 32; off >= 1; off >>= 1) {
            mxB = fmaxf(mxB, __shfl_xor(mxB, off));
            mnB = fminf(mnB, __shfl_xor(mnB, off));
        }
        if (lane == 0 && pB < Pdim) {
            pBmx[slot] = mxB;
            pBmn[slot] = mnB;
        }
    }
}

// Epilogue: one wave per m. Reconstructs per-p max/min from the <=5 covering
// wave slots, sums the 100 per-p terms + damping, writes out[m].
__global__ __launch_bounds__(64)
void epilogue_kernel(const float* __restrict__ pAmx, const float* __restrict__ pAmn,
                     const float* __restrict__ pBmx, const float* __restrict__ pBmn,
                     const float* __restrict__ e00f, const float* __restrict__ bvel,
                     float* __restrict__ out)
{
    const int m    = blockIdx.x;
    const int lane = threadIdx.x;

    float acc = 0.0f;
    for (int p = lane; p < Pdim; p += 64) {
        const int w0 = (EVALS_PER_P * p) / EVALS_PER_WAVE;
        const int w1 = (EVALS_PER_P * p + NCdim - 1) / EVALS_PER_WAVE;
        float mx = -FLT_MAX, mn = FLT_MAX;
        for (int w = w0; w <= w1; ++w) {
            const int s = m * WAVES_PER_M + w;
            const int pAw = (w * EVALS_PER_WAVE) / EVALS_PER_P;
            const float vmx = (pAw == p) ? pAmx[s] : pBmx[s];
            const float vmn = (pAw == p) ? pAmn[s] : pBmn[s];
            mx = fmaxf(mx, vmx);
            mn = fminf(mn, vmn);
        }
        const float en = e00f[m * Pdim + p] / (mx - mn);
        acc += 1.0f - __builtin_amdgcn_exp2f(fabsf(en) * LOG2_10TH); // 1-0.1^|en|
    }

    // damping term
    float damp = 0.0f;
    if (lane < Ldim) {
        const float bb    = bvel[m * Ldim + lane];
        const float bprev = bvel[m * Ldim + ((lane == 0) ? 0 : lane - 1)];
        const float bnext = bvel[m * Ldim + ((lane == Ldim - 1) ? Ldim - 1 : lane + 1)];
        float tval;
        if (lane == 0)             tval = bb - bnext;
        else if (lane == Ldim - 1) tval = bb - bprev;
        else                       tval = 2.0f * bb - bprev - bnext;
        damp = fabsf(tval * (1.0f / (float)Ldim));
    }

    float tot = fmaf(acc, 1.0f / (float)Pdim, damp);
    for (int off = 32; off >= 1; off >>= 1)
        tot += __shfl_xor(tot, off);
    if (lane == 0) out[m] = tot;
}

extern "C" void kernel_launch(void* const* d_in, const int* in_sizes, int n_in,
                              void* d_out, int out_size, void* d_ws, size_t ws_size,
                              hipStream_t stream)
{
    const float* vlist = (const float*)d_in[0];
    const float* tlist = (const float*)d_in[1];
    const float* dth   = (const float*)d_in[2];
    const float* bvel  = (const float*)d_in[3];
    const float* Clist = (const float*)d_in[4];
    float* out = (float*)d_out;

    float* pAmx = (float*)d_ws;            // [WSLOT]
    float* pAmn = pAmx + WSLOT;
    float* pBmx = pAmn + WSLOT;
    float* pBmn = pBmx + WSLOT;
    float* e00f = pBmn + WSLOT;            // [NPTS]

    hipLaunchKernelGGL(disp_kernel, dim3(Mdim * BLOCKS_PER_M), dim3(256), 0, stream,
                       vlist, tlist, dth, bvel, Clist, pAmx, pAmn, pBmx, pBmn, e00f);
    hipLaunchKernelGGL(epilogue_kernel, dim3(Mdim), dim3(64), 0, stream,
                       pAmx, pAmn, pBmx, pBmn, e00f, bvel, out);
}